// Round 14
// baseline (688.233 us; speedup 1.0000x reference)
//
#include <hip/hip_runtime.h>
#include <hip/hip_bf16.h>
#include <stdint.h>

#define N_NODES 262144
#define E_EDGES 4194304
#define SRC_OFF 524288
#define DST_OFF (524288 + 4194310)
#define W_OFF   (524288 + 2 * 4194310)
#define NSEG    64
#define SEG3    4608               // per-seg cap, mean 4096 sigma 62 (+8.2s)
#define SEG2X   13568              // per-seg cap, mean 12288 sigma 100 (+12.8s)
#define T3      (NSEG * SEG3)      // 294912
#define T2X     (NSEG * SEG2X)     // 868352
#define SCAT1_BLOCKS (E_EDGES * 16 / 256)   // 262144
#define OUT_BLOCKS   (E_EDGES / 8 / 256)    // 2048

using bf16 = __hip_bfloat16;
typedef float f4v __attribute__((ext_vector_type(4)));
typedef float f2v __attribute__((ext_vector_type(2)));

__device__ __forceinline__ float b2f(unsigned int u) {
    union { unsigned int i; float f; } v; v.i = u << 16; return v.f;
}

// raw packed 2xbf16 atomic add (fire-and-forget; hs pre-scaled by dinv[s])
__device__ __forceinline__ void pk_atomic_add_raw(bf16* addr, uint32_t data) {
    asm volatile("global_atomic_pk_add_bf16 %0, %1, off" :: "v"(addr), "v"(data) : "memory");
}

// inline symmetric-norm factor: dinv(i) = rsqrt(deg[i] + 1 [+1 if pad endpoint])
__device__ __forceinline__ float dinv_of(const float* __restrict__ deg, int i, int n, int pads) {
    float extra = (pads && (i == 0 || i == n - 1)) ? 1.0f : 0.0f;
    return rsqrtf(deg[i] + 1.0f + extra);
}

// ---------------------------------------------------------------------------
// 1) prep: ONE pass over ei. deg1/2/3 scattered atomics + segmented
// compaction: per-wave tier totals (shfl reduce) -> bulk reservation via
// atomicAdd on cnt[wid&63] (128 waves/counter, 2 returns/wave) -> ballot-
// prefix placement. el3 = packed u32 (s | d<<16, both < 65536); el2x = int2.
// ---------------------------------------------------------------------------
__global__ void __launch_bounds__(256) prep_kernel(const int* __restrict__ ei,
        uint32_t* __restrict__ el3, int2* __restrict__ el2,
        uint32_t* __restrict__ cnt3, uint32_t* __restrict__ cnt2,
        float* __restrict__ deg1, float* __restrict__ deg2, float* __restrict__ deg3) {
    int t = blockIdx.x * 256 + threadIdx.x;          // t < E/8 = 524288
    int lane = threadIdx.x & 63;
    int seg = (t >> 6) & (NSEG - 1);
    int4 s0 = ((const int4*)ei)[2 * t];
    int4 s1 = ((const int4*)ei)[2 * t + 1];
    int4 d0 = ((const int4*)(ei + E_EDGES))[2 * t];
    int4 d1 = ((const int4*)(ei + E_EDGES))[2 * t + 1];

    atomicAdd(&deg1[d0.x], 1.0f); atomicAdd(&deg1[d0.y], 1.0f);
    atomicAdd(&deg1[d0.z], 1.0f); atomicAdd(&deg1[d0.w], 1.0f);
    atomicAdd(&deg1[d1.x], 1.0f); atomicAdd(&deg1[d1.y], 1.0f);
    atomicAdd(&deg1[d1.z], 1.0f); atomicAdd(&deg1[d1.w], 1.0f);

    int ss[8] = {s0.x, s0.y, s0.z, s0.w, s1.x, s1.y, s1.z, s1.w};
    int dd[8] = {d0.x, d0.y, d0.z, d0.w, d1.x, d1.y, d1.z, d1.w};
    int c3 = 0, c2 = 0;
#pragma unroll
    for (int j = 0; j < 8; ++j) {
        bool b3  = (ss[j] < 65536) & (dd[j] < 65536);
        bool b23 = (ss[j] < 131072) & (dd[j] < 131072);
        c3 += b3; c2 += (b23 & !b3);
    }
    int pk = c2 | (c3 << 16);   // wave sums <= 512 per field, no overflow
    pk += __shfl_xor(pk, 32); pk += __shfl_xor(pk, 16); pk += __shfl_xor(pk, 8);
    pk += __shfl_xor(pk, 4);  pk += __shfl_xor(pk, 2);  pk += __shfl_xor(pk, 1);
    uint32_t wt2 = (uint32_t)pk & 0xFFFFu, wt3 = (uint32_t)pk >> 16;
    uint32_t b3base = 0, b2base = 0;
    if (lane == 0) {
        b3base = atomicAdd(&cnt3[seg], wt3);
        b2base = atomicAdd(&cnt2[seg], wt2);
    }
    b3base = __shfl(b3base, 0, 64);
    b2base = __shfl(b2base, 0, 64);
    uint32_t r3 = b3base, r2 = b2base;
    uint64_t lt = (1ull << lane) - 1ull;
#pragma unroll
    for (int j = 0; j < 8; ++j) {
        int s = ss[j], d = dd[j];
        bool b3  = (s < 65536) & (d < 65536);
        bool b23 = (s < 131072) & (d < 131072);
        bool b2  = b23 & !b3;
        uint64_t m3 = __ballot(b3), m2 = __ballot(b2);
        if (b3) {
            uint32_t pos = r3 + (uint32_t)__popcll(m3 & lt);
            if (pos < SEG3) el3[seg * SEG3 + pos] = (uint32_t)s | ((uint32_t)d << 16);
            atomicAdd(&deg3[d], 1.0f);
        }
        if (b2) {
            uint32_t pos = r2 + (uint32_t)__popcll(m2 & lt);
            if (pos < SEG2X) el2[seg * SEG2X + pos] = make_int2(s, d);
        }
        if (b23) atomicAdd(&deg2[d], 1.0f);
        r3 += (uint32_t)__popcll(m3); r2 += (uint32_t)__popcll(m2);
    }
}

// ---------------------------------------------------------------------------
// 2a) xform (stage 1): hs = dinv1*(x@W) bf16; agg init = hs (self-loop term).
// ---------------------------------------------------------------------------
__global__ void __launch_bounds__(256) xform1_kernel(const float* __restrict__ xin,
        const float* __restrict__ W, const float* __restrict__ deg1,
        bf16* __restrict__ hs, bf16* __restrict__ agg) {
    constexpr int FIN = 32, FOUT = 32, NPB = 8;
    __shared__ float sW[FIN * FOUT];
    __shared__ float sx[NPB * FIN];
    int tid = threadIdx.x;
    for (int i = tid; i < FIN * FOUT; i += 256) sW[i] = W[i];
    int node0 = blockIdx.x * NPB;
    for (int i = tid; i < NPB * FIN; i += 256) sx[i] = xin[node0 * FIN + i];
    __syncthreads();
    int nl = tid / FOUT, j = tid % FOUT;
    int node = node0 + nl;
    float acc = 0.0f;
#pragma unroll
    for (int k = 0; k < FIN; ++k) acc += sx[nl * FIN + k] * sW[k * FOUT + j];
    bf16 v = __float2bfloat16(rsqrtf(deg1[node] + 1.0f) * acc);
    hs[node * FOUT + j]  = v;
    agg[node * FOUT + j] = v;
}

// ---------------------------------------------------------------------------
// 2b) xform_pool (stages 2/3): pool previous agg inline during staging, then
// hs = dinv*(x@W); agg init = hs. dinv recomputed inline from deg.
// ---------------------------------------------------------------------------
template <int FOUT>
__global__ void __launch_bounds__(256) xform_pool_kernel(const bf16* __restrict__ aggp,
        const float* __restrict__ degp, int prevN, int prevPads, const float* __restrict__ biasp,
        const float* __restrict__ W, const float* __restrict__ deg, int curN,
        bf16* __restrict__ hs, bf16* __restrict__ agg) {
    constexpr int FIN = 32;
    constexpr int NPB = 256 / FOUT;
    __shared__ float sW[FIN * FOUT];
    __shared__ float sx[NPB * FIN];
    const unsigned short* ap = (const unsigned short*)aggp;
    int tid = threadIdx.x;
    for (int i = tid; i < FIN * FOUT; i += 256) sW[i] = W[i];
    int node0 = blockIdx.x * NPB;
    for (int i = tid; i < NPB * FIN; i += 256) {
        int nl = i / FIN, k = i % FIN;
        int g0 = 2 * (node0 + nl);
        float bb = biasp[k];
        float v0 = dinv_of(degp, g0,     prevN, prevPads) * b2f(ap[(size_t)g0 * FIN + k])       + bb;
        float v1 = dinv_of(degp, g0 + 1, prevN, prevPads) * b2f(ap[(size_t)(g0 + 1) * FIN + k]) + bb;
        sx[i] = fmaxf(fmaxf(v0, v1), 0.0f);
    }
    __syncthreads();
    int nl = tid / FOUT, j = tid % FOUT;
    int node = node0 + nl;
    float acc = 0.0f;
#pragma unroll
    for (int k = 0; k < FIN; ++k) acc += sx[nl * FIN + k] * sW[k * FOUT + j];
    bf16 v = __float2bfloat16(dinv_of(deg, node, curN, 1) * acc);
    hs[node * FOUT + j]  = v;
    agg[node * FOUT + j] = v;
}

// ---------------------------------------------------------------------------
// 3) scatter1 + fused edge outputs: blocks [0, SCAT1) do the flat pk-atomic
// scatter (atomic-unit-bound, 70% HBM headroom); blocks [SCAT1, SCAT1+OUT)
// stream the 100 MB src/dst/w outputs UNDER the atomic bottleneck for free.
// ---------------------------------------------------------------------------
__global__ void __launch_bounds__(256) scatter1_kernel(const int* __restrict__ ei,
        const bf16* __restrict__ hs, bf16* __restrict__ agg, float* __restrict__ out) {
    if (blockIdx.x >= SCAT1_BLOCKS) {
        int t = (blockIdx.x - SCAT1_BLOCKS) * 256 + threadIdx.x;   // t < E/8
        int4 s0 = ((const int4*)ei)[2 * t];
        int4 s1 = ((const int4*)ei)[2 * t + 1];
        int4 d0 = ((const int4*)(ei + E_EDGES))[2 * t];
        int4 d1 = ((const int4*)(ei + E_EDGES))[2 * t + 1];
        f4v v;
        v = (f4v){(float)s0.x, (float)s0.y, (float)s0.z, (float)s0.w};
        __builtin_nontemporal_store(v, (f4v*)(out + SRC_OFF) + 2 * t);
        v = (f4v){(float)s1.x, (float)s1.y, (float)s1.z, (float)s1.w};
        __builtin_nontemporal_store(v, (f4v*)(out + SRC_OFF) + 2 * t + 1);
        f2v w2;
        w2 = (f2v){(float)d0.x, (float)d0.y}; __builtin_nontemporal_store(w2, (f2v*)(out + DST_OFF) + 4 * t);
        w2 = (f2v){(float)d0.z, (float)d0.w}; __builtin_nontemporal_store(w2, (f2v*)(out + DST_OFF) + 4 * t + 1);
        w2 = (f2v){(float)d1.x, (float)d1.y}; __builtin_nontemporal_store(w2, (f2v*)(out + DST_OFF) + 4 * t + 2);
        w2 = (f2v){(float)d1.z, (float)d1.w}; __builtin_nontemporal_store(w2, (f2v*)(out + DST_OFF) + 4 * t + 3);
        v = (f4v){(s0.x < 32768 && d0.x < 32768) ? 1.0f : 0.0f,
                  (s0.y < 32768 && d0.y < 32768) ? 1.0f : 0.0f,
                  (s0.z < 32768 && d0.z < 32768) ? 1.0f : 0.0f,
                  (s0.w < 32768 && d0.w < 32768) ? 1.0f : 0.0f};
        __builtin_nontemporal_store(v, (f4v*)(out + W_OFF) + 2 * t);
        v = (f4v){(s1.x < 32768 && d1.x < 32768) ? 1.0f : 0.0f,
                  (s1.y < 32768 && d1.y < 32768) ? 1.0f : 0.0f,
                  (s1.z < 32768 && d1.z < 32768) ? 1.0f : 0.0f,
                  (s1.w < 32768 && d1.w < 32768) ? 1.0f : 0.0f};
        __builtin_nontemporal_store(v, (f4v*)(out + W_OFF) + 2 * t + 1);
        if (blockIdx.x == SCAT1_BLOCKS && threadIdx.x < 6) {   // pad slots E..E+5
            int k = threadIdx.x;
            int stage = k >> 1, m = 131072 >> stage;
            int s, d;
            if ((k & 1) == 0) { s = m - 1; d = 0; } else { s = 0; d = m - 1; }
            int e = E_EDGES + k;
            out[SRC_OFF + e] = (float)s;
            out[DST_OFF + e] = (float)d;
            out[W_OFF + e]   = (stage == 2) ? 1.0f : 0.0f;
        }
        return;
    }
    unsigned idx = blockIdx.x * 256u + threadIdx.x;
    int e = (int)(idx >> 4), p = (int)(idx & 15u);
    int s = ei[e], d = ei[E_EDGES + e];
    uint32_t hw = *(const uint32_t*)((const unsigned short*)hs + (size_t)s * 32 + 2 * p);
    pk_atomic_add_raw(agg + (size_t)d * 32 + 2 * p, hw);
}

// ---------------------------------------------------------------------------
// 4) scatter2: el3 segments + el2x segments + 2 pads (n = 131072).
// ---------------------------------------------------------------------------
__global__ void __launch_bounds__(256) scatter2_kernel(const uint32_t* __restrict__ el3,
        const int2* __restrict__ el2, const uint32_t* __restrict__ cnt3,
        const uint32_t* __restrict__ cnt2, const bf16* __restrict__ hs,
        bf16* __restrict__ agg) {
    unsigned idx = blockIdx.x * 256u + threadIdx.x;
    unsigned e = idx >> 4; int p = (int)(idx & 15u);
    int s, d;
    if (e < T3) {
        unsigned seg = e / SEG3, loc = e - seg * SEG3;
        if (loc >= cnt3[seg]) return;
        uint32_t v = el3[e];
        s = (int)(v & 0xFFFFu); d = (int)(v >> 16);
    } else if (e < T3 + T2X) {
        unsigned e2 = e - T3, seg = e2 / SEG2X, loc = e2 - seg * SEG2X;
        if (loc >= cnt2[seg]) return;
        int2 sd = el2[e2]; s = sd.x; d = sd.y;
    } else if (e == T3 + T2X)     { s = 131071; d = 0; }
    else if (e == T3 + T2X + 1)   { s = 0; d = 131071; }
    else return;
    uint32_t hw = *(const uint32_t*)((const unsigned short*)hs + (size_t)s * 32 + 2 * p);
    pk_atomic_add_raw(agg + (size_t)d * 32 + 2 * p, hw);
}

// ---------------------------------------------------------------------------
// 5) scatter3: el3 segments + 2 pads (n = 65536), FOUT = 16.
// ---------------------------------------------------------------------------
__global__ void __launch_bounds__(256) scatter3_kernel(const uint32_t* __restrict__ el3,
        const uint32_t* __restrict__ cnt3, const bf16* __restrict__ hs,
        bf16* __restrict__ agg) {
    unsigned idx = blockIdx.x * 256u + threadIdx.x;
    unsigned e = idx >> 3; int p = (int)(idx & 7u);
    int s, d;
    if (e < T3) {
        unsigned seg = e / SEG3, loc = e - seg * SEG3;
        if (loc >= cnt3[seg]) return;
        uint32_t v = el3[e];
        s = (int)(v & 0xFFFFu); d = (int)(v >> 16);
    } else if (e == T3)     { s = 65535; d = 0; }
    else if (e == T3 + 1)   { s = 0; d = 65535; }
    else return;
    uint32_t hw = *(const uint32_t*)((const unsigned short*)hs + (size_t)s * 16 + 2 * p);
    pk_atomic_add_raw(agg + (size_t)d * 16 + 2 * p, hw);
}

// ---------------------------------------------------------------------------
// 6) final pool: out(f32) = relu(max over pair of dinv3*agg3 + b3)
// ---------------------------------------------------------------------------
__global__ void __launch_bounds__(256) pool_out_kernel(const bf16* __restrict__ agg,
        const float* __restrict__ deg3, const float* __restrict__ bias,
        float* __restrict__ outp) {
    unsigned idx = blockIdx.x * 256u + threadIdx.x;   // < 32768*16
    int i = (int)(idx >> 4), f = (int)(idx & 15);
    int g0 = 2 * i;
    float bb = bias[f];
    float v0 = dinv_of(deg3, g0,     65536, 1) * __bfloat162float(agg[(size_t)g0 * 16 + f])       + bb;
    float v1 = dinv_of(deg3, g0 + 1, 65536, 1) * __bfloat162float(agg[(size_t)(g0 + 1) * 16 + f]) + bb;
    outp[idx] = fmaxf(fmaxf(v0, v1), 0.0f);
}

// ---------------------------------------------------------------------------
// Workspace (<57 MiB):
//  @0M  agg bf16 (16/8/2 MB per stage)   @16M hs bf16 (16/8/2 MB)
//  @44M el3 u32 (1.2 MB)   @46M el2x int2 (6.7 MB)
//  @55M deg1 (1M) @56M deg2 (.5M) @56.5M deg3 (.25M) @56.75M cnt3[64],cnt2[64]
// ---------------------------------------------------------------------------
extern "C" void kernel_launch(void* const* d_in, const int* in_sizes, int n_in,
                              void* d_out, int out_size, void* d_ws, size_t ws_size,
                              hipStream_t stream) {
    const float* x  = (const float*)d_in[0];
    const int*   ei = (const int*)d_in[1];
    const float* W1 = (const float*)d_in[2];
    const float* b1 = (const float*)d_in[3];
    const float* W2 = (const float*)d_in[4];
    const float* b2 = (const float*)d_in[5];
    const float* W3 = (const float*)d_in[6];
    const float* b3 = (const float*)d_in[7];
    float* out = (float*)d_out;

    char* ws = (char*)d_ws;
    bf16*     agg   = (bf16*)ws;
    bf16*     hs    = (bf16*)(ws + (16u << 20));
    uint32_t* el3   = (uint32_t*)(ws + (44u << 20));
    int2*     el2   = (int2*)(ws + (46u << 20));
    float*    deg1  = (float*)(ws + (55u << 20));
    float*    deg2  = (float*)(ws + (56u << 20));
    float*    deg3  = (float*)(ws + (56u << 20) + (512u << 10));
    uint32_t* cnt3  = (uint32_t*)(ws + (56u << 20) + (768u << 10));
    uint32_t* cnt2  = cnt3 + NSEG;

    // zero deg1+deg2+deg3+cnt3+cnt2 (contiguous 1.75 MB + 512 B)
    hipMemsetAsync(deg1, 0, (1u << 20) + (768u << 10) + 512u, stream);

    // single-pass prep: degs + segmented compaction
    prep_kernel<<<2048, 256, 0, stream>>>(ei, el3, el2, cnt3, cnt2, deg1, deg2, deg3);

    // stage 1: n=262144, 32->32 (all edges; ei directly; outputs ride along)
    xform1_kernel<<<N_NODES / 8, 256, 0, stream>>>(x, W1, deg1, hs, agg);
    scatter1_kernel<<<SCAT1_BLOCKS + OUT_BLOCKS, 256, 0, stream>>>(ei, hs, agg, out);

    // stage 2: n=131072, 32->32 (pool fused into xform; segmented el + pads)
    xform_pool_kernel<32><<<131072 / 8, 256, 0, stream>>>(agg, deg1, 262144, 0, b1,
                                                          W2, deg2, 131072, hs, agg);
    scatter2_kernel<<<(int)((((unsigned)(T3 + T2X + 2)) * 16 + 255) / 256), 256, 0, stream>>>(
        el3, el2, cnt3, cnt2, hs, agg);

    // stage 3: n=65536, 32->16 (pool fused; el3 prefix + pads)
    xform_pool_kernel<16><<<65536 / 16, 256, 0, stream>>>(agg, deg2, 131072, 1, b2,
                                                          W3, deg3, 65536, hs, agg);
    scatter3_kernel<<<(int)((((unsigned)(T3 + 2)) * 8 + 255) / 256), 256, 0, stream>>>(
        el3, cnt3, hs, agg);

    // final pool -> f32 out
    pool_out_kernel<<<32768 * 16 / 256, 256, 0, stream>>>(agg, deg3, b3, out);
}